// Round 3
// baseline (227.531 us; speedup 1.0000x reference)
//
#include <hip/hip_runtime.h>
#include <math.h>

// TopKRouter: x[16384,2048] fp32, W[64,2048] fp32
// out: [0..32767] top2 indices (as float), [32768..65535] gates, [65536] aux
// Split-fp16 MFMA (3-term: xh*wh + xh*wl + xl*wh).
// R3: barrier-free K-loop. A-fragment loaded DIRECTLY from global x
// (lane = row lane&15, k=(lane>>4)*8+j -> 8 consecutive floats = 2x float4),
// converted h/l in registers -- no LDS staging, no __syncthreads in the loop,
// no cross-wave lockstep. Each wave computes ALL 64 experts (4 B-blocks,
// 12 MFMA/step); K split 2 ways per token-tile to reach 8 waves/CU.
// Deadline-ordered issue (W-prefetch before x-prefetch) so FIFO vmcnt waits
// never force-drain the depth-4 x ring. x read exactly once (134 MB).
#define NTOK 16384
#define DDIM 2048
#define NEXP 64
#define TMB  32                 // tokens per block (2 MFMA M-tiles)
#define NBLK (NTOK / TMB)       // 512 blocks -> 2 blocks/CU, 8 waves/CU
#define NSW  32                 // K32 steps per wave (K-split 2: K=1024 each)

typedef _Float16 half8v __attribute__((ext_vector_type(8)));
typedef float    f32x4  __attribute__((ext_vector_type(4)));

#define MFMA16(a, b, c) __builtin_amdgcn_mfma_f32_16x16x32_f16((a), (b), (c), 0, 0, 0)

// W prep: fp32 -> (wh, wl) fp16 in MFMA-B fragment-linear layout (r5-verified):
// element (e,k): S=k>>5, nb=e>>4, nl=e&15, q=(k>>3)&3, j=k&7
// off = S*2048 + nb*512 + q*128 + nl*8 + j
__global__ __launch_bounds__(256) void prep_kernel(const float* __restrict__ W,
                                                   _Float16* __restrict__ Wh,
                                                   _Float16* __restrict__ Wl,
                                                   float* __restrict__ accg) {
    int idx = blockIdx.x * 256 + threadIdx.x;   // 64 blocks -> 16384 threads
    int e  = idx >> 8;                          // 0..63
    int k0 = (idx & 255) << 3;                  // 0..2040, multiple of 8
    const float* wp = W + (size_t)e * DDIM + k0;
    float4 w0 = *(const float4*)wp;
    float4 w1 = *(const float4*)(wp + 4);
    half8v h, l;
    h[0] = (_Float16)w0.x; l[0] = (_Float16)(w0.x - (float)h[0]);
    h[1] = (_Float16)w0.y; l[1] = (_Float16)(w0.y - (float)h[1]);
    h[2] = (_Float16)w0.z; l[2] = (_Float16)(w0.z - (float)h[2]);
    h[3] = (_Float16)w0.w; l[3] = (_Float16)(w0.w - (float)h[3]);
    h[4] = (_Float16)w1.x; l[4] = (_Float16)(w1.x - (float)h[4]);
    h[5] = (_Float16)w1.y; l[5] = (_Float16)(w1.y - (float)h[5]);
    h[6] = (_Float16)w1.z; l[6] = (_Float16)(w1.z - (float)h[6]);
    h[7] = (_Float16)w1.w; l[7] = (_Float16)(w1.w - (float)h[7]);
    int S = k0 >> 5, nb = e >> 4, nl = e & 15, q = (k0 >> 3) & 3;
    size_t off = (size_t)S * 2048 + nb * 512 + q * 128 + nl * 8;
    *(half8v*)&Wh[off] = h;
    *(half8v*)&Wl[off] = l;
    if (idx < 128) accg[idx] = 0.0f;
}

__global__ __launch_bounds__(256, 2) void router_kernel(
    const float* __restrict__ x, const _Float16* __restrict__ Wh,
    const _Float16* __restrict__ Wl, float* __restrict__ accg,
    float* __restrict__ out)
{
    __shared__ float pacc[2][64][16];       // 8 KB: K-half-1 partials
    __shared__ float lgt[TMB][NEXP + 1];    // 8.3 KB
    __shared__ float cnt[NEXP];

    const int tid  = threadIdx.x;
    const int lane = tid & 63;
    const int wv   = __builtin_amdgcn_readfirstlane(tid >> 6);  // 0..3
    const int th   = wv & 1;        // token half (0: tokens 0-15, 1: 16-31)
    const int qk   = wv >> 1;       // K half (0: k<1024, 1: k>=1024)
    const int m0   = blockIdx.x * TMB;

    if (tid < NEXP) cnt[tid] = 0.0f;

    // A-frag direct: row = lane&15, k = qk*1024 + S*32 + (lane>>4)*8 + j
    const int row = m0 + th * 16 + (lane & 15);
    const float* gxp = x + (size_t)row * DDIM + qk * 1024 + (lane >> 4) * 8;

    // B-frag bases (frag-linear, step stride 2048 halfs, eblock stride 512)
    const _Float16* wbh = Wh + (size_t)qk * (NSW * 2048) + lane * 8;
    const _Float16* wbl = Wl + (size_t)qk * (NSW * 2048) + lane * 8;

    f32x4 acc0 = {0.f,0.f,0.f,0.f}, acc1 = {0.f,0.f,0.f,0.f};
    f32x4 acc2 = {0.f,0.f,0.f,0.f}, acc3 = {0.f,0.f,0.f,0.f};

    // prologue: x ring depth 4 (steps 0..3), W ring depth 2 (steps 0,1)
    float4 xA0 = *(const float4*)(gxp +   0), xB0 = *(const float4*)(gxp +   4);
    float4 xA1 = *(const float4*)(gxp +  32), xB1 = *(const float4*)(gxp +  36);
    float4 xA2 = *(const float4*)(gxp +  64), xB2 = *(const float4*)(gxp +  68);
    float4 xA3 = *(const float4*)(gxp +  96), xB3 = *(const float4*)(gxp + 100);
    half8v h0a = *(const half8v*)(wbh +    0), h1a = *(const half8v*)(wbh +  512);
    half8v h2a = *(const half8v*)(wbh + 1024), h3a = *(const half8v*)(wbh + 1536);
    half8v l0a = *(const half8v*)(wbl +    0), l1a = *(const half8v*)(wbl +  512);
    half8v l2a = *(const half8v*)(wbl + 1024), l3a = *(const half8v*)(wbl + 1536);
    half8v h0b = *(const half8v*)(wbh + 2048), h1b = *(const half8v*)(wbh + 2560);
    half8v h2b = *(const half8v*)(wbh + 3072), h3b = *(const half8v*)(wbh + 3584);
    half8v l0b = *(const half8v*)(wbl + 2048), l1b = *(const half8v*)(wbl + 2560);
    half8v l2b = *(const half8v*)(wbl + 3072), l3b = *(const half8v*)(wbl + 3584);

    // One K32 step. Order matters for FIFO vmcnt: cvt (waits x(S)) ->
    // W-prefetch(S+2) -> MFMAs (wait W(S); x(S+1..) issued after W(S) stay
    // in flight) -> x-prefetch(S+4) last.
#define STEP(S, XA, XB, H0,H1,H2,H3, L0,L1,L2,L3)                           \
    {                                                                        \
        half8v ah, al;                                                       \
        ah[0]=(_Float16)XA.x; al[0]=(_Float16)(XA.x-(float)ah[0]);           \
        ah[1]=(_Float16)XA.y; al[1]=(_Float16)(XA.y-(float)ah[1]);           \
        ah[2]=(_Float16)XA.z; al[2]=(_Float16)(XA.z-(float)ah[2]);           \
        ah[3]=(_Float16)XA.w; al[3]=(_Float16)(XA.w-(float)ah[3]);           \
        ah[4]=(_Float16)XB.x; al[4]=(_Float16)(XB.x-(float)ah[4]);           \
        ah[5]=(_Float16)XB.y; al[5]=(_Float16)(XB.y-(float)ah[5]);           \
        ah[6]=(_Float16)XB.z; al[6]=(_Float16)(XB.z-(float)ah[6]);           \
        ah[7]=(_Float16)XB.w; al[7]=(_Float16)(XB.w-(float)ah[7]);           \
        half8v bh0=H0, bl0=L0, bh1=H1, bl1=L1;                               \
        half8v bh2=H2, bl2=L2, bh3=H3, bl3=L3;                               \
        const int Sw_ = ((S) + 2 < NSW) ? (S) + 2 : 0;                       \
        const _Float16* whs = wbh + (size_t)Sw_ * 2048;                      \
        const _Float16* wls = wbl + (size_t)Sw_ * 2048;                      \
        H0 = *(const half8v*)(whs +    0); L0 = *(const half8v*)(wls +    0);\
        H1 = *(const half8v*)(whs +  512); L1 = *(const half8v*)(wls +  512);\
        H2 = *(const half8v*)(whs + 1024); L2 = *(const half8v*)(wls + 1024);\
        H3 = *(const half8v*)(whs + 1536); L3 = *(const half8v*)(wls + 1536);\
        acc0 = MFMA16(al, bh0, acc0);                                        \
        acc0 = MFMA16(ah, bl0, acc0);                                        \
        acc0 = MFMA16(ah, bh0, acc0);                                        \
        acc1 = MFMA16(al, bh1, acc1);                                        \
        acc1 = MFMA16(ah, bl1, acc1);                                        \
        acc1 = MFMA16(ah, bh1, acc1);                                        \
        acc2 = MFMA16(al, bh2, acc2);                                        \
        acc2 = MFMA16(ah, bl2, acc2);                                        \
        acc2 = MFMA16(ah, bh2, acc2);                                        \
        acc3 = MFMA16(al, bh3, acc3);                                        \
        acc3 = MFMA16(ah, bl3, acc3);                                        \
        acc3 = MFMA16(ah, bh3, acc3);                                        \
        const int Sx_ = ((S) + 4 < NSW) ? (S) + 4 : 0;                       \
        XA = *(const float4*)(gxp + Sx_ * 32);                               \
        XB = *(const float4*)(gxp + Sx_ * 32 + 4);                           \
    }

    for (int s = 0; s < NSW; s += 4) {
        STEP(s + 0, xA0, xB0, h0a,h1a,h2a,h3a, l0a,l1a,l2a,l3a);
        STEP(s + 1, xA1, xB1, h0b,h1b,h2b,h3b, l0b,l1b,l2b,l3b);
        STEP(s + 2, xA2, xB2, h0a,h1a,h2a,h3a, l0a,l1a,l2a,l3a);
        STEP(s + 3, xA3, xB3, h0b,h1b,h2b,h3b, l0b,l1b,l2b,l3b);
    }
#undef STEP

    // ---- combine K-halves: waves 2,3 park partials; waves 0,1 add ----
    if (wv >= 2) {
        #pragma unroll
        for (int r = 0; r < 4; ++r) {
            pacc[th][lane][ 0 + r] = acc0[r];
            pacc[th][lane][ 4 + r] = acc1[r];
            pacc[th][lane][ 8 + r] = acc2[r];
            pacc[th][lane][12 + r] = acc3[r];
        }
    }
    __syncthreads();

    // ---- C layout: row m=(lane>>4)*4+r, col n=lane&15 (m89/r5-verified) ----
    if (wv < 2) {
        const int qr = lane >> 4;
        const int nl = lane & 15;
        #pragma unroll
        for (int r = 0; r < 4; ++r) {
            const int m = th * 16 + qr * 4 + r;
            lgt[m][ 0 + nl] = acc0[r] + pacc[th][lane][ 0 + r];
            lgt[m][16 + nl] = acc1[r] + pacc[th][lane][ 4 + r];
            lgt[m][32 + nl] = acc2[r] + pacc[th][lane][ 8 + r];
            lgt[m][48 + nl] = acc3[r] + pacc[th][lane][12 + r];
        }
    }
    __syncthreads();

    // ---- softmax + top-2: 8 threads per token (32 tok x 8 = 256 thr) ----
    {
        const int m = tid >> 3;
        const int j = tid & 7;
        float l[8];
        #pragma unroll
        for (int i = 0; i < 8; ++i) l[i] = lgt[m][j * 8 + i];

        float mx = l[0];
        #pragma unroll
        for (int i = 1; i < 8; ++i) mx = fmaxf(mx, l[i]);
        #pragma unroll
        for (int off = 1; off < 8; off <<= 1) mx = fmaxf(mx, __shfl_xor(mx, off, 8));

        float ev[8];
        float zs = 0.f;
        float v1 = -INFINITY, v2 = -INFINITY;
        int i1 = 0, i2 = 0;
        #pragma unroll
        for (int i = 0; i < 8; ++i) {
            ev[i] = __expf(l[i] - mx);
            zs += ev[i];
            int e = j * 8 + i;
            if (l[i] > v1)      { v2 = v1; i2 = i1; v1 = l[i]; i1 = e; }
            else if (l[i] > v2) { v2 = l[i]; i2 = e; }
        }
        #pragma unroll
        for (int off = 1; off < 8; off <<= 1) zs += __shfl_xor(zs, off, 8);

        // merge top-2 across 8 lanes (value desc, index asc on ties = lax.top_k)
        #pragma unroll
        for (int off = 1; off < 8; off <<= 1) {
            float ov1 = __shfl_xor(v1, off, 8);
            int   oi1 = __shfl_xor(i1, off, 8);
            float ov2 = __shfl_xor(v2, off, 8);
            int   oi2 = __shfl_xor(i2, off, 8);
            bool afirst = (v1 > ov1) || (v1 == ov1 && i1 < oi1);
            if (afirst) {
                bool t = (v2 > ov1) || (v2 == ov1 && i2 < oi1);
                v2 = t ? v2 : ov1;
                i2 = t ? i2 : oi1;
            } else {
                bool t = (ov2 > v1) || (ov2 == v1 && oi2 < i1);
                v2 = t ? ov2 : v1;
                i2 = t ? oi2 : i1;
                v1 = ov1;
                i1 = oi1;
            }
        }

        const float invz = 1.0f / zs;
        if (j == 0) {
            float p1 = invz;                      // v1 == mx exactly
            float p2 = __expf(v2 - mx) * invz;
            float sden = p1 + p2 + 1e-9f;
            int tok = m0 + m;
            out[tok * 2 + 0] = (float)i1;
            out[tok * 2 + 1] = (float)i2;
            out[32768 + tok * 2 + 0] = p1 / sden;
            out[32768 + tok * 2 + 1] = p2 / sden;
            atomicAdd(&cnt[i1], 1.0f);
            atomicAdd(&cnt[i2], 1.0f);
        }

        // probs writeback (own slots only)
        #pragma unroll
        for (int i = 0; i < 8; ++i) lgt[m][j * 8 + i] = ev[i] * invz;
    }
    __syncthreads();

    // global accumulators (accg zeroed by prep each launch)
    if (tid < NEXP) {
        atomicAdd(&accg[tid], cnt[tid]);
    } else if (tid < 128) {
        int e = tid - 64;
        float s = 0.f;
        #pragma unroll
        for (int t = 0; t < TMB; ++t) s += lgt[t][e];
        atomicAdd(&accg[64 + e], s);
    }
}

__global__ void finalize_kernel(const float* __restrict__ accg,
                                float* __restrict__ out)
{
    int t = threadIdx.x;   // 64 threads
    float c = accg[t];
    float p = accg[64 + t];
    float term = (c / (float)(NTOK * 2)) * (p / (float)NTOK);
    #pragma unroll
    for (int off = 1; off < 64; off <<= 1) term += __shfl_xor(term, off, 64);
    if (t == 0) out[65536] = 0.01f * (float)NEXP * term;
}

extern "C" void kernel_launch(void* const* d_in, const int* in_sizes, int n_in,
                              void* d_out, int out_size, void* d_ws, size_t ws_size,
                              hipStream_t stream) {
    const float* x = (const float*)d_in[0];   // [4,4096,2048]
    const float* W = (const float*)d_in[1];   // [64,2048]
    float* out  = (float*)d_out;              // 65537 floats
    float* accg = (float*)d_ws;               // 128 floats
    _Float16* Wh = (_Float16*)(accg + 128);   // 131072 halfs (256 KB)
    _Float16* Wl = Wh + (size_t)DDIM * NEXP;  // 131072 halfs (256 KB)

    prep_kernel<<<64, 256, 0, stream>>>(W, Wh, Wl, accg);
    router_kernel<<<NBLK, 256, 0, stream>>>(x, Wh, Wl, accg, out);
    finalize_kernel<<<1, 64, 0, stream>>>(accg, out);
}

// Round 5
// 226.139 us; speedup vs baseline: 1.0062x; 1.0062x over previous
//
#include <hip/hip_runtime.h>
#include <math.h>

// TopKRouter: x[16384,2048] fp32, W[64,2048] fp32
// out: [0..32767] top2 indices (as float), [32768..65535] gates, [65536] aux
// Split-fp16 MFMA (3-term: xh*wh + xh*wl + xl*wh).
// R4/R5: global_load_lds + counted-vmcnt pipeline (T3/T4, m201/m218 pattern).
// R3 post-mortem: named-register rings were collapsed by the register
// allocator (VGPR_Count=72 < ring size) -- source-level reg pipelining loses.
// global_load_lds has NO dest VGPRs, so the pipeline survives codegen:
//   x: fp32 staged in frag-order, 3 LDS bufs, staged 2 chunks ahead
//   W: (h,l) frag-linear, 2 LDS bufs, staged 1 chunk ahead
//   per chunk: 6 gload_lds/wave; end: vmcnt(2) keeps x(ch+2) in flight
//   across the raw s_barrier (never drain to 0 in the loop).
// R5 = R4 resubmitted verbatim: R4's bench died on container acquisition
// (no counters); audit found no hang/fault mechanism in the kernel.
#define NTOK 16384
#define DDIM 2048
#define NEXP 64
#define TMB  32                 // tokens per block (2 MFMA M-tiles)
#define NBLK (NTOK / TMB)       // 512 blocks -> 2 blocks/CU
#define NCH  32                 // K chunks of 64 (2 K32 steps each)

typedef _Float16 half8v __attribute__((ext_vector_type(8)));
typedef float    f32x4  __attribute__((ext_vector_type(4)));

#define MFMA16(a, b, c) __builtin_amdgcn_mfma_f32_16x16x32_f16((a), (b), (c), 0, 0, 0)

__device__ __forceinline__ void stage16(const void* g, void* l) {
    __builtin_amdgcn_global_load_lds(
        (const __attribute__((address_space(1))) unsigned int*)g,
        (__attribute__((address_space(3))) unsigned int*)l, 16, 0, 0);
}

// W prep: fp32 -> (wh, wl) fp16 in MFMA-B fragment-linear layout (r5-verified):
// element (e,k): S=k>>5, nb=e>>4, nl=e&15, q=(k>>3)&3, j=k&7
// off = S*2048 + nb*512 + q*128 + nl*8 + j
__global__ __launch_bounds__(256) void prep_kernel(const float* __restrict__ W,
                                                   _Float16* __restrict__ Wh,
                                                   _Float16* __restrict__ Wl,
                                                   float* __restrict__ accg) {
    int idx = blockIdx.x * 256 + threadIdx.x;   // 64 blocks -> 16384 threads
    int e  = idx >> 8;                          // 0..63
    int k0 = (idx & 255) << 3;                  // 0..2040, multiple of 8
    const float* wp = W + (size_t)e * DDIM + k0;
    float4 w0 = *(const float4*)wp;
    float4 w1 = *(const float4*)(wp + 4);
    half8v h, l;
    h[0] = (_Float16)w0.x; l[0] = (_Float16)(w0.x - (float)h[0]);
    h[1] = (_Float16)w0.y; l[1] = (_Float16)(w0.y - (float)h[1]);
    h[2] = (_Float16)w0.z; l[2] = (_Float16)(w0.z - (float)h[2]);
    h[3] = (_Float16)w0.w; l[3] = (_Float16)(w0.w - (float)h[3]);
    h[4] = (_Float16)w1.x; l[4] = (_Float16)(w1.x - (float)h[4]);
    h[5] = (_Float16)w1.y; l[5] = (_Float16)(w1.y - (float)h[5]);
    h[6] = (_Float16)w1.z; l[6] = (_Float16)(w1.z - (float)h[6]);
    h[7] = (_Float16)w1.w; l[7] = (_Float16)(w1.w - (float)h[7]);
    int S = k0 >> 5, nb = e >> 4, nl = e & 15, q = (k0 >> 3) & 3;
    size_t off = (size_t)S * 2048 + nb * 512 + q * 128 + nl * 8;
    *(half8v*)&Wh[off] = h;
    *(half8v*)&Wl[off] = l;
    if (idx < 128) accg[idx] = 0.0f;
}

__global__ __launch_bounds__(256, 2) void router_kernel(
    const float* __restrict__ x, const _Float16* __restrict__ Wh,
    const _Float16* __restrict__ Wl, float* __restrict__ accg,
    float* __restrict__ out)
{
    // x frag-order fp32: combo c=(th*2+s)*2+h, lane's 16B at [c*256 + lane*4]
    __shared__ __align__(16) float    Xs[3][2048];   // 24 KB, 3-deep
    __shared__ __align__(16) _Float16 Ws[2][2][4096];// [h/l][buf][..] 32 KB
    __shared__ float lgt[TMB][NEXP + 1];             // 8.3 KB
    __shared__ float cnt[NEXP];

    const int tid  = threadIdx.x;
    const int lane = tid & 63;
    const int wv   = __builtin_amdgcn_readfirstlane(tid >> 6);  // 0..3
    const int th   = wv & 1;        // compute: token half
    const int eh   = wv >> 1;       // compute: expert half (2 eblocks)
    const int m0   = blockIdx.x * TMB;

    if (tid < NEXP) cnt[tid] = 0.0f;

    // ---- staging addresses (wave w stages combos 2w,2w+1: th=w>>1,s=w&1) ----
    const int sth = wv >> 1, sst = wv & 1;
    const float* gx0 = x + (size_t)(m0 + sth * 16 + (lane & 15)) * DDIM
                         + sst * 32 + (lane >> 4) * 8;          // h=0 16B
    const float* gx1 = gx0 + 4;                                  // h=1 16B
    float* xdst0 = &Xs[0][(2 * wv) * 256];      // + BX*2048
    float* xdst1 = &Xs[0][(2 * wv + 1) * 256];
    // W: waves 0,1 stage Wh regions (wv&1)*4..+3; waves 2,3 stage Wl same
    const _Float16* wgsrc = (wv < 2 ? Wh : Wl) + (wv & 1) * 2048 + lane * 8;
    _Float16* wdbase = &Ws[eh][0][(wv & 1) * 2048];  // + BW*4096

#define STAGE_W(CW, BW)                                                      \
    {                                                                        \
        const _Float16* ws_ = wgsrc + (size_t)(CW) * 4096;                   \
        _Float16* wd_ = wdbase + (BW) * 4096;                                \
        stage16(ws_,        wd_);                                            \
        stage16(ws_ +  512, wd_ +  512);                                     \
        stage16(ws_ + 1024, wd_ + 1024);                                     \
        stage16(ws_ + 1536, wd_ + 1536);                                     \
    }
#define STAGE_X(CS, BX)                                                      \
    {                                                                        \
        stage16(gx0 + (size_t)(CS) * 64, xdst0 + (BX) * 2048);               \
        stage16(gx1 + (size_t)(CS) * 64, xdst1 + (BX) * 2048);               \
    }

    // ---- compute-side read pointers ----
    const float* xrd = &Xs[0][th * 1024 + lane * 4];          // + xb*2048 + s*512 (+256 for h=1)
    const _Float16* whrd = &Ws[0][0][eh * 1024 + lane * 8];   // + wb*4096 + s*2048 (+512 for nb1)
    const _Float16* wlrd = &Ws[1][0][eh * 1024 + lane * 8];

    f32x4 acc0 = {0.f, 0.f, 0.f, 0.f}, acc1 = {0.f, 0.f, 0.f, 0.f};

    // ---- prologue: W(0)->buf0, x(0)->buf0, x(1)->buf1; keep x(1) in flight
    STAGE_W(0, 0);
    STAGE_X(0, 0);
    STAGE_X(1, 1);
    __builtin_amdgcn_sched_barrier(0);
    asm volatile("s_waitcnt vmcnt(2) lgkmcnt(0)" ::: "memory");
    __builtin_amdgcn_s_barrier();
    __builtin_amdgcn_sched_barrier(0);

    int xb = 0, xsb = 2;
    for (int ch = 0; ch < NCH; ++ch) {
        const int wb = ch & 1;
        int cw = ch + 1; if (cw >= NCH) cw = 0;      // W chunk to stage (wrap)
        int cs = ch + 2; if (cs >= NCH) cs -= NCH;   // x chunk to stage (wrap)
        STAGE_W(cw, wb ^ 1);
        STAGE_X(cs, xsb);

        #pragma unroll
        for (int s = 0; s < 2; ++s) {
            const float4 xa  = *(const float4*)(xrd + xb * 2048 + s * 512);
            const float4 xbv = *(const float4*)(xrd + xb * 2048 + s * 512 + 256);
            half8v ah, al;
            ah[0]=(_Float16)xa.x;  al[0]=(_Float16)(xa.x -(float)ah[0]);
            ah[1]=(_Float16)xa.y;  al[1]=(_Float16)(xa.y -(float)ah[1]);
            ah[2]=(_Float16)xa.z;  al[2]=(_Float16)(xa.z -(float)ah[2]);
            ah[3]=(_Float16)xa.w;  al[3]=(_Float16)(xa.w -(float)ah[3]);
            ah[4]=(_Float16)xbv.x; al[4]=(_Float16)(xbv.x-(float)ah[4]);
            ah[5]=(_Float16)xbv.y; al[5]=(_Float16)(xbv.y-(float)ah[5]);
            ah[6]=(_Float16)xbv.z; al[6]=(_Float16)(xbv.z-(float)ah[6]);
            ah[7]=(_Float16)xbv.w; al[7]=(_Float16)(xbv.w-(float)ah[7]);
            half8v bh0 = *(const half8v*)(whrd + wb * 4096 + s * 2048);
            half8v bl0 = *(const half8v*)(wlrd + wb * 4096 + s * 2048);
            half8v bh1 = *(const half8v*)(whrd + wb * 4096 + s * 2048 + 512);
            half8v bl1 = *(const half8v*)(wlrd + wb * 4096 + s * 2048 + 512);
            acc0 = MFMA16(al, bh0, acc0);
            acc0 = MFMA16(ah, bl0, acc0);
            acc0 = MFMA16(ah, bh0, acc0);
            acc1 = MFMA16(al, bh1, acc1);
            acc1 = MFMA16(ah, bl1, acc1);
            acc1 = MFMA16(ah, bh1, acc1);
        }

        // counted vmcnt: outstanding = x(ch+1)[2] + W(ch+1)[4] + x(ch+2)[2];
        // vmcnt(2) drains x(ch+1)+W(ch+1), keeps x(ch+2) in flight.
        __builtin_amdgcn_sched_barrier(0);
        asm volatile("s_waitcnt vmcnt(2) lgkmcnt(0)" ::: "memory");
        __builtin_amdgcn_s_barrier();
        __builtin_amdgcn_sched_barrier(0);

        xb  = (xb  == 2) ? 0 : xb  + 1;
        xsb = (xsb == 2) ? 0 : xsb + 1;
    }
#undef STAGE_W
#undef STAGE_X

    // ---- C layout: row m=(lane>>4)*4+r, col n=lane&15 (m89/r5-verified) ----
    {
        const int qr = lane >> 4;
        const int nl = lane & 15;
        #pragma unroll
        for (int r = 0; r < 4; ++r) {
            const int m = th * 16 + qr * 4 + r;
            lgt[m][(eh * 2 + 0) * 16 + nl] = acc0[r];
            lgt[m][(eh * 2 + 1) * 16 + nl] = acc1[r];
        }
    }
    __syncthreads();

    // ---- softmax + top-2: 8 threads per token (32 tok x 8 = 256 thr) ----
    {
        const int m = tid >> 3;
        const int j = tid & 7;
        float l[8];
        #pragma unroll
        for (int i = 0; i < 8; ++i) l[i] = lgt[m][j * 8 + i];

        float mx = l[0];
        #pragma unroll
        for (int i = 1; i < 8; ++i) mx = fmaxf(mx, l[i]);
        #pragma unroll
        for (int off = 1; off < 8; off <<= 1) mx = fmaxf(mx, __shfl_xor(mx, off, 8));

        float ev[8];
        float zs = 0.f;
        float v1 = -INFINITY, v2 = -INFINITY;
        int i1 = 0, i2 = 0;
        #pragma unroll
        for (int i = 0; i < 8; ++i) {
            ev[i] = __expf(l[i] - mx);
            zs += ev[i];
            int e = j * 8 + i;
            if (l[i] > v1)      { v2 = v1; i2 = i1; v1 = l[i]; i1 = e; }
            else if (l[i] > v2) { v2 = l[i]; i2 = e; }
        }
        #pragma unroll
        for (int off = 1; off < 8; off <<= 1) zs += __shfl_xor(zs, off, 8);

        // merge top-2 across 8 lanes (value desc, index asc on ties = lax.top_k)
        #pragma unroll
        for (int off = 1; off < 8; off <<= 1) {
            float ov1 = __shfl_xor(v1, off, 8);
            int   oi1 = __shfl_xor(i1, off, 8);
            float ov2 = __shfl_xor(v2, off, 8);
            int   oi2 = __shfl_xor(i2, off, 8);
            bool afirst = (v1 > ov1) || (v1 == ov1 && i1 < oi1);
            if (afirst) {
                bool t = (v2 > ov1) || (v2 == ov1 && i2 < oi1);
                v2 = t ? v2 : ov1;
                i2 = t ? i2 : oi1;
            } else {
                bool t = (ov2 > v1) || (ov2 == v1 && oi2 < i1);
                v2 = t ? ov2 : v1;
                i2 = t ? oi2 : i1;
                v1 = ov1;
                i1 = oi1;
            }
        }

        const float invz = 1.0f / zs;
        if (j == 0) {
            float p1 = invz;                      // v1 == mx exactly
            float p2 = __expf(v2 - mx) * invz;
            float sden = p1 + p2 + 1e-9f;
            int tok = m0 + m;
            out[tok * 2 + 0] = (float)i1;
            out[tok * 2 + 1] = (float)i2;
            out[32768 + tok * 2 + 0] = p1 / sden;
            out[32768 + tok * 2 + 1] = p2 / sden;
            atomicAdd(&cnt[i1], 1.0f);
            atomicAdd(&cnt[i2], 1.0f);
        }

        // probs writeback (own slots only)
        #pragma unroll
        for (int i = 0; i < 8; ++i) lgt[m][j * 8 + i] = ev[i] * invz;
    }
    __syncthreads();

    // global accumulators (accg zeroed by prep each launch)
    if (tid < NEXP) {
        atomicAdd(&accg[tid], cnt[tid]);
    } else if (tid < 128) {
        int e = tid - 64;
        float s = 0.f;
        #pragma unroll
        for (int t = 0; t < TMB; ++t) s += lgt[t][e];
        atomicAdd(&accg[64 + e], s);
    }
}

__global__ void finalize_kernel(const float* __restrict__ accg,
                                float* __restrict__ out)
{
    int t = threadIdx.x;   // 64 threads
    float c = accg[t];
    float p = accg[64 + t];
    float term = (c / (float)(NTOK * 2)) * (p / (float)NTOK);
    #pragma unroll
    for (int off = 1; off < 64; off <<= 1) term += __shfl_xor(term, off, 64);
    if (t == 0) out[65536] = 0.01f * (float)NEXP * term;
}

extern "C" void kernel_launch(void* const* d_in, const int* in_sizes, int n_in,
                              void* d_out, int out_size, void* d_ws, size_t ws_size,
                              hipStream_t stream) {
    const float* x = (const float*)d_in[0];   // [4,4096,2048]
    const float* W = (const float*)d_in[1];   // [64,2048]
    float* out  = (float*)d_out;              // 65537 floats
    float* accg = (float*)d_ws;               // 128 floats
    _Float16* Wh = (_Float16*)(accg + 128);   // 131072 halfs (256 KB)
    _Float16* Wl = Wh + (size_t)DDIM * NEXP;  // 131072 halfs (256 KB)

    prep_kernel<<<64, 256, 0, stream>>>(W, Wh, Wl, accg);
    router_kernel<<<NBLK, 256, 0, stream>>>(x, Wh, Wl, accg, out);
    finalize_kernel<<<1, 64, 0, stream>>>(accg, out);
}